// Round 4
// baseline (363.781 us; speedup 1.0000x reference)
//
#include <hip/hip_runtime.h>

#define ADAM_B1 0.9f
#define ADAM_B2 0.999f
#define ADAM_LR 1e-3f
#define ADAM_EPS 1e-8f

// clang-native 16B vector: required by __builtin_nontemporal_load/store
// (HIP's float4 is a class type the builtin rejects).
typedef float f32x4 __attribute__((ext_vector_type(4)));

#define RPH 4   // rows per half-wave: 4 concurrent emb loads/lane = 4x MLP

// K1: one thread per occurrence. Build per-row linked list of occurrences:
//   next[occ] = atomicExch(&head[row], occ)
// head[] must be -1-initialized (memset 0xFF) before this kernel.
__global__ void k_build_list(const int* __restrict__ idx, int* __restrict__ head,
                             int* __restrict__ next_, int n_idx) {
    int i = blockIdx.x * blockDim.x + threadIdx.x;
    if (i >= n_idx) return;
    int row = idx[i];
    next_[i] = atomicExch(&head[row], i);
}

__device__ __forceinline__ void adam_update(
        float stepn, f32x4 e, f32x4 m, f32x4 pv, f32x4 g, f32x4* o4) {
    // pow(b, s) = exp2(s * log2(b)) -- single v_exp_f32 each
    const float L2B1 = -0.15200309344504997f;     // log2(0.9)
    const float L2B2 = -0.0014434592066161948f;   // log2(0.999)
    float inv_d1 = 1.0f / (1.0f - exp2f(stepn * L2B1));
    float inv_d2 = 1.0f / (1.0f - exp2f(stepn * L2B2));

    f32x4 r;
    {
        float mx = ADAM_B1 * m.x + (1.0f - ADAM_B1) * g.x;
        float px = ADAM_B2 * pv.x + (1.0f - ADAM_B2) * g.x * g.x;
        r.x = e.x - ADAM_LR * (mx * inv_d1) / (sqrtf(px * inv_d2) + ADAM_EPS);
        float my = ADAM_B1 * m.y + (1.0f - ADAM_B1) * g.y;
        float py = ADAM_B2 * pv.y + (1.0f - ADAM_B2) * g.y * g.y;
        r.y = e.y - ADAM_LR * (my * inv_d1) / (sqrtf(py * inv_d2) + ADAM_EPS);
        float mz = ADAM_B1 * m.z + (1.0f - ADAM_B1) * g.z;
        float pz = ADAM_B2 * pv.z + (1.0f - ADAM_B2) * g.z * g.z;
        r.z = e.z - ADAM_LR * (mz * inv_d1) / (sqrtf(pz * inv_d2) + ADAM_EPS);
        float mw = ADAM_B1 * m.w + (1.0f - ADAM_B1) * g.w;
        float pw = ADAM_B2 * pv.w + (1.0f - ADAM_B2) * g.w * g.w;
        r.w = e.w - ADAM_LR * (mw * inv_d1) / (sqrtf(pw * inv_d2) + ADAM_EPS);
    }
    __builtin_nontemporal_store(r, o4);
}

// K2: fused sparse Adam. One half-wave (32 lanes) per RPH consecutive rows.
//
// v4 structure: issue all RPH emb loads + RPH head loads up front
// (4x memory-level parallelism per lane, amortized wave launch), then
// resolve each row: untouched -> single store of the already-loaded e
// (head has long since resolved, so the branch costs no extra latency);
// touched -> chain-walk grads, Adam, single store. No duplicate stores.
//
// Non-temporal hints on all single-use streams (emb/out/mem/pow/grad)
// keep L2 available for head[]/next_[] chain walks.
__global__ __launch_bounds__(256) void k_adam_fused(
        const float* __restrict__ emb,
        const float* __restrict__ step_,
        const float* __restrict__ mem_,
        const float* __restrict__ pow_,
        const float* __restrict__ grad,
        const int* __restrict__ head,
        const int* __restrict__ next_,
        float* __restrict__ out, int n_emb, int D) {
    int gid = blockIdx.x * blockDim.x + threadIdx.x;
    int hw  = gid >> 5;                 // half-wave id
    int lane = threadIdx.x & 31;
    long long row0 = (long long)hw * RPH;
    if (row0 >= n_emb) return;
    int nrows = n_emb - row0 >= RPH ? RPH : (int)(n_emb - row0);

    if (D == 128) {
        // fast path: each lane owns f32x4 #lane of each row (32*16B = 512B = row)
        f32x4 e[RPH];
        int   h[RPH];
        #pragma unroll
        for (int k = 0; k < RPH; ++k) {
            long long r = (k < nrows) ? row0 + k : row0;   // clamp: safe addr
            e[k] = __builtin_nontemporal_load((const f32x4*)(emb + r * 128) + lane);
            h[k] = head[r];
        }
        #pragma unroll
        for (int k = 0; k < RPH; ++k) {
            if (k >= nrows) break;
            long long r = row0 + k;
            f32x4* o4 = (f32x4*)(out + r * 128) + lane;
            if (h[k] < 0) {                 // untouched: single store, done
                __builtin_nontemporal_store(e[k], o4);
                continue;
            }
            // touched: chain-walk grads (avg ~1.13 hops), Adam update
            float stepn = step_[r] + 1.0f;
            f32x4 m  = __builtin_nontemporal_load((const f32x4*)(mem_ + r * 128) + lane);
            f32x4 pv = __builtin_nontemporal_load((const f32x4*)(pow_ + r * 128) + lane);
            f32x4 g = (f32x4)(0.0f);
            float cnt = 0.0f;
            int p = h[k];
            while (p >= 0) {
                g += __builtin_nontemporal_load((const f32x4*)(grad + (long long)p * 128) + lane);
                cnt += 1.0f;
                p = next_[p];
            }
            g *= (1.0f / cnt);
            adam_update(stepn, e[k], m, pv, g, o4);
        }
    } else {
        // generic fallback: per-row column loop (unused for this problem's D=128)
        int nv = D >> 2;
        for (int k = 0; k < nrows; ++k) {
            long long r = row0 + k;
            long long base = r * D;
            const f32x4* e4 = (const f32x4*)(emb + base);
            f32x4* o4 = (f32x4*)(out + base);
            int h = head[r];
            for (int c = lane; c < nv; c += 32) {
                f32x4 e = __builtin_nontemporal_load(e4 + c);
                if (h < 0) { __builtin_nontemporal_store(e, o4 + c); continue; }
                float stepn = step_[r] + 1.0f;
                f32x4 m  = __builtin_nontemporal_load((const f32x4*)(mem_ + base) + c);
                f32x4 pv = __builtin_nontemporal_load((const f32x4*)(pow_ + base) + c);
                f32x4 g = (f32x4)(0.0f);
                float cnt = 0.0f;
                int p = h;
                while (p >= 0) {
                    g += __builtin_nontemporal_load((const f32x4*)(grad + (long long)p * D) + c);
                    cnt += 1.0f;
                    p = next_[p];
                }
                g *= (1.0f / cnt);
                adam_update(stepn, e, m, pv, g, o4 + c);
            }
        }
    }
}

extern "C" void kernel_launch(void* const* d_in, const int* in_sizes, int n_in,
                              void* d_out, int out_size, void* d_ws, size_t ws_size,
                              hipStream_t stream) {
    const int*   idx   = (const int*)d_in[0];
    const float* grad  = (const float*)d_in[1];
    const float* emb   = (const float*)d_in[2];
    const float* step_ = (const float*)d_in[3];
    const float* mem_  = (const float*)d_in[4];
    const float* pow_  = (const float*)d_in[5];
    float* out = (float*)d_out;

    int n_idx = in_sizes[0];
    int n_emb = in_sizes[3];               // state_step is [N_EMB]
    int D     = in_sizes[1] / n_idx;       // 128

    int* head  = (int*)d_ws;               // n_emb ints
    int* next_ = head + n_emb;             // n_idx ints

    (void)hipMemsetAsync(head, 0xFF, (size_t)n_emb * sizeof(int), stream);  // all -1

    const int blk = 256;
    k_build_list<<<(n_idx + blk - 1) / blk, blk, 0, stream>>>(idx, head, next_, n_idx);

    long long n_hw = ((long long)n_emb + RPH - 1) / RPH;   // half-waves
    long long threads = n_hw * 32;
    k_adam_fused<<<(int)((threads + blk - 1) / blk), blk, 0, stream>>>(
        emb, step_, mem_, pow_, grad, head, next_, out, n_emb, D);
}